// Round 3
// baseline (511.066 us; speedup 1.0000x reference)
//
#include <hip/hip_runtime.h>
#include <hip/hip_bf16.h>
#include <math.h>

#define B_ROWS 1024
#define V_COLS 50257
#define E_DIM  128
#define NTILES 393                 // ceil(V_COLS / 128)
#define VPAD   (NTILES * 128)      // 50304
#define TPB    3                   // n-tiles per block
#define NX     131                 // blocks along n: NX*TPB == NTILES exactly
#define N4     (V_COLS * E_DIM / 4)
#define N4P    (VPAD * E_DIM / 4)

typedef __attribute__((ext_vector_type(8))) short short8;
typedef __attribute__((ext_vector_type(4))) float floatx4;

static __device__ __forceinline__ unsigned short f2bf(float x) {
    union { float f; unsigned int u; } c; c.f = x;
    unsigned int u = c.u;
    unsigned int r = u + 0x7fffu + ((u >> 16) & 1u);
    return (unsigned short)(r >> 16);
}

// ---------------------------------------------------------------- find one-hot index
__global__ void find_idx_kernel(const float4* __restrict__ xs4, int* __restrict__ idx) {
    long i = (long)blockIdx.x * blockDim.x + threadIdx.x;
    const long n4 = (long)B_ROWS * V_COLS / 4;
    if (i >= n4) return;
    float4 v = xs4[i];
    float vals[4] = {v.x, v.y, v.z, v.w};
    #pragma unroll
    for (int c = 0; c < 4; ++c) {
        if (vals[c] != 0.0f) {
            long f = 4 * i + c;
            int b = (int)(f / V_COLS);
            idx[b] = (int)(f - (long)b * V_COLS);
        }
    }
}

// ---------------------------------------------------------------- NEG fp32 -> bf16 (padded to VPAD rows, zeros)
__global__ void cvt_bf16_kernel(const float4* __restrict__ src, ushort4* __restrict__ dst) {
    int i = blockIdx.x * blockDim.x + threadIdx.x;
    if (i >= N4P) return;
    ushort4 o;
    if (i < N4) {
        float4 v = src[i];
        o.x = f2bf(v.x); o.y = f2bf(v.y); o.z = f2bf(v.z); o.w = f2bf(v.w);
    } else {
        o.x = 0; o.y = 0; o.z = 0; o.w = 0;
    }
    dst[i] = o;
}

// ---------------------------------------------------------------- t[b] = EMBEDM[idx[b]] @ metric  (bf16 out)
__global__ void compute_t_kernel(const float* __restrict__ EMB, const float* __restrict__ metric,
                                 const int* __restrict__ idx, unsigned short* __restrict__ t) {
    __shared__ float erow[E_DIM];
    int b = blockIdx.x, tid = threadIdx.x;
    int id = idx[b];
    erow[tid] = EMB[(long)id * E_DIM + tid];
    __syncthreads();
    float acc = 0.f;
    #pragma unroll 16
    for (int k = 0; k < E_DIM; ++k) acc += erow[k] * metric[k * E_DIM + tid];
    t[b * E_DIM + tid] = f2bf(acc);
}

// ---------------------------------------------------------------- LDS-free MFMA GEMM: scores = t @ neg^T
// grid (8, NX): blockIdx.x = m-block (128 rows), blockIdx.y = n-group (TPB tiles of 128 cols).
// 256 threads = 4 waves in 2x2; per wave: A frags (64x128) resident in VGPRs, B frags loaded
// per-lane from global per tile — no LDS, no barriers in the hot loop, compiler pipelines
// B-loads of tile i+1 against MFMA of tile i.
// Stats pass: online softmax (running m,s per row-slot in registers), LDS only for the
// final wn-half merge. Write pass: direct global stores from accs, minus preloaded lse.
template <bool WRITE_OUT>
__global__ __launch_bounds__(256, 2) void gemm_kernel(const unsigned short* __restrict__ t,
                                                      const unsigned short* __restrict__ neg,
                                                      float2* __restrict__ partials,
                                                      const float* __restrict__ lse,
                                                      float* __restrict__ out) {
    __shared__ float2 stats[2][128];

    const int tid  = threadIdx.x;
    const int lane = tid & 63, wave = tid >> 6;
    const int l16  = lane & 15, q = lane >> 4;
    const int wm   = wave >> 1, wn = wave & 1;
    const int mbase = blockIdx.x * 128;
    const int tile0 = blockIdx.y * TPB;

    // ---- resident A fragments: rows mbase + wm*64 + mf*16 + l16, k = ks*32 + q*8
    short8 af[4][4];
    #pragma unroll
    for (int mf = 0; mf < 4; ++mf) {
        const unsigned short* arow = t + (size_t)(mbase + wm * 64 + mf * 16 + l16) * E_DIM + q * 8;
        #pragma unroll
        for (int ks = 0; ks < 4; ++ks)
            af[mf][ks] = *(const short8*)(arow + ks * 32);
    }

    float lsev[4][4];
    float rm[4][4], rs[4][4];
    if (WRITE_OUT) {
        #pragma unroll
        for (int mf = 0; mf < 4; ++mf)
            #pragma unroll
            for (int r = 0; r < 4; ++r)
                lsev[mf][r] = lse[mbase + wm * 64 + mf * 16 + q * 4 + r];
    } else {
        #pragma unroll
        for (int mf = 0; mf < 4; ++mf)
            #pragma unroll
            for (int r = 0; r < 4; ++r) { rm[mf][r] = -1e30f; rs[mf][r] = 0.f; }
    }

    for (int it = 0; it < TPB; ++it) {
        const int colbase = (tile0 + it) * 128 + wn * 64;

        // ---- B fragments: col n = colbase + nt*16 + l16, k = ks*32 + q*8
        short8 bf[4][4];
        #pragma unroll
        for (int nt = 0; nt < 4; ++nt) {
            const unsigned short* brow = neg + (size_t)(colbase + nt * 16 + l16) * E_DIM + q * 8;
            #pragma unroll
            for (int ks = 0; ks < 4; ++ks)
                bf[nt][ks] = *(const short8*)(brow + ks * 32);
        }

        floatx4 acc[4][4];
        #pragma unroll
        for (int mf = 0; mf < 4; ++mf)
            #pragma unroll
            for (int nt = 0; nt < 4; ++nt) acc[mf][nt] = (floatx4){0, 0, 0, 0};

        #pragma unroll
        for (int ks = 0; ks < 4; ++ks)
            #pragma unroll
            for (int mf = 0; mf < 4; ++mf)
                #pragma unroll
                for (int nt = 0; nt < 4; ++nt)
                    acc[mf][nt] = __builtin_amdgcn_mfma_f32_16x16x32_bf16(af[mf][ks], bf[nt][ks], acc[mf][nt], 0, 0, 0);

        // acc[mf][nt][r]: row = mbase + wm*64 + mf*16 + q*4 + r, col = colbase + nt*16 + l16
        if (WRITE_OUT) {
            #pragma unroll
            for (int nt = 0; nt < 4; ++nt) {
                const int col = colbase + nt * 16 + l16;
                if (col < V_COLS) {
                    #pragma unroll
                    for (int mf = 0; mf < 4; ++mf) {
                        const size_t rb = (size_t)(mbase + wm * 64 + mf * 16 + q * 4) * V_COLS + col;
                        #pragma unroll
                        for (int r = 0; r < 4; ++r)
                            out[rb + (size_t)r * V_COLS] = acc[mf][nt][r] - lsev[mf][r];
                    }
                }
            }
        } else {
            bool ok[4];
            #pragma unroll
            for (int nt = 0; nt < 4; ++nt) ok[nt] = (colbase + nt * 16 + l16) < V_COLS;
            #pragma unroll
            for (int mf = 0; mf < 4; ++mf)
                #pragma unroll
                for (int r = 0; r < 4; ++r) {
                    float m = rm[mf][r], s = rs[mf][r];
                    #pragma unroll
                    for (int nt = 0; nt < 4; ++nt) {
                        float v = acc[mf][nt][r];
                        float mm = ok[nt] ? fmaxf(m, v) : m;
                        s = s * __expf(m - mm) + (ok[nt] ? __expf(v - mm) : 0.f);
                        m = mm;
                    }
                    rm[mf][r] = m; rs[mf][r] = s;
                }
        }
    }

    if (!WRITE_OUT) {
        // cross-lane reduce over the 16 lanes sharing each row (same q, varying l16)
        #pragma unroll
        for (int mf = 0; mf < 4; ++mf)
            #pragma unroll
            for (int r = 0; r < 4; ++r) {
                float m = rm[mf][r], s = rs[mf][r];
                #pragma unroll
                for (int d = 1; d < 16; d <<= 1) {
                    float m2 = __shfl_xor(m, d, 16);
                    float s2 = __shfl_xor(s, d, 16);
                    float mm = fmaxf(m, m2);
                    s = s * __expf(m - mm) + s2 * __expf(m2 - mm);
                    m = mm;
                }
                if (l16 == 0) stats[wn][wm * 64 + mf * 16 + q * 4 + r] = make_float2(m, s);
            }
        __syncthreads();
        if (tid < 128) {
            float2 p0 = stats[0][tid], p1 = stats[1][tid];
            float mm = fmaxf(p0.x, p1.x);
            float ss = p0.y * __expf(p0.x - mm) + p1.y * __expf(p1.x - mm);
            partials[(long)(mbase + tid) * NX + blockIdx.y] = make_float2(mm, ss);
        }
    }
}

// ---------------------------------------------------------------- merge per-block (m,s) partials -> lse[b]
__global__ void merge_lse_kernel(const float2* __restrict__ partials, float* __restrict__ lse) {
    int b = blockIdx.x;
    int tid = threadIdx.x;
    float m = -1e30f, s = 0.f;
    for (int i = tid; i < NX; i += 256) {
        float2 p = partials[(long)b * NX + i];
        float mm = fmaxf(m, p.x);
        s = s * __expf(m - mm) + p.y * __expf(p.x - mm);
        m = mm;
    }
    __shared__ float sm[256], ss[256];
    sm[tid] = m; ss[tid] = s;
    __syncthreads();
    for (int off = 128; off > 0; off >>= 1) {
        if (tid < off) {
            float m1 = sm[tid], s1 = ss[tid];
            float m2 = sm[tid + off], s2 = ss[tid + off];
            float mm = fmaxf(m1, m2);
            sm[tid] = mm;
            ss[tid] = s1 * __expf(m1 - mm) + s2 * __expf(m2 - mm);
        }
        __syncthreads();
    }
    if (tid == 0) lse[b] = sm[0] + __logf(ss[0]);
}

// ---------------------------------------------------------------- launch
extern "C" void kernel_launch(void* const* d_in, const int* in_sizes, int n_in,
                              void* d_out, int out_size, void* d_ws, size_t ws_size,
                              hipStream_t stream) {
    const float* xs     = (const float*)d_in[0];
    const float* metric = (const float*)d_in[1];
    const float* EMB    = (const float*)d_in[2];
    const float* NEG    = (const float*)d_in[3];
    float* out = (float*)d_out;

    char* ws = (char*)d_ws;
    // layout: idx[1024] | t bf16[1024*128] | neg bf16[VPAD*128] | partials float2[1024*NX] | lse[1024]
    int*            idx      = (int*)ws;                               // 4096 B
    unsigned short* t        = (unsigned short*)(ws + 4096);           // 262144 -> 266240
    unsigned short* neg16    = (unsigned short*)(ws + 266240);         // VPAD*128*2 = 12877824 -> 13144064
    float2*         partials = (float2*)(ws + 13144064);               // 1024*131*8 = 1073152 -> 14217216
    float*          lse      = (float*)(ws + 14217216);                // 4096 B

    {
        long n4 = (long)B_ROWS * V_COLS / 4;
        int blocks = (int)((n4 + 255) / 256);
        find_idx_kernel<<<blocks, 256, 0, stream>>>((const float4*)xs, idx);
    }
    cvt_bf16_kernel<<<(N4P + 255) / 256, 256, 0, stream>>>((const float4*)NEG, (ushort4*)neg16);
    compute_t_kernel<<<B_ROWS, E_DIM, 0, stream>>>(EMB, metric, idx, t);
    gemm_kernel<false><<<dim3(8, NX), 256, 0, stream>>>(t, neg16, partials, nullptr, nullptr);
    merge_lse_kernel<<<B_ROWS, 256, 0, stream>>>(partials, lse);
    gemm_kernel<true><<<dim3(8, NX), 256, 0, stream>>>(t, neg16, partials, lse, out);
}

// Round 4
// 469.287 us; speedup vs baseline: 1.0890x; 1.0890x over previous
//
#include <hip/hip_runtime.h>
#include <hip/hip_bf16.h>
#include <math.h>

#define B_ROWS 1024
#define V_COLS 50257
#define E_DIM  128
#define NTILES 393                 // ceil(V_COLS / 128)
#define VPAD   (NTILES * 128)      // 50304
#define TPB    3                   // n-tiles per block
#define NX     131                 // NX*TPB == NTILES exactly
#define N4     (V_COLS * E_DIM / 4)
#define N4P    (VPAD * E_DIM / 4)

typedef __attribute__((ext_vector_type(8))) short short8;
typedef __attribute__((ext_vector_type(4))) float floatx4;

// async global->LDS, 16B per lane; LDS dest is wave-uniform base + lane*16
#define GLOAD_LDS16(g, l) \
    __builtin_amdgcn_global_load_lds((const __attribute__((address_space(1))) void*)(g), \
                                     (__attribute__((address_space(3))) void*)(l), 16, 0, 0)

static __device__ __forceinline__ unsigned short f2bf(float x) {
    union { float f; unsigned int u; } c; c.f = x;
    unsigned int u = c.u;
    unsigned int r = u + 0x7fffu + ((u >> 16) & 1u);
    return (unsigned short)(r >> 16);
}

// ---------------------------------------------------------------- find one-hot index
__global__ void find_idx_kernel(const float4* __restrict__ xs4, int* __restrict__ idx) {
    long i = (long)blockIdx.x * blockDim.x + threadIdx.x;
    const long n4 = (long)B_ROWS * V_COLS / 4;
    if (i >= n4) return;
    float4 v = xs4[i];
    float vals[4] = {v.x, v.y, v.z, v.w};
    #pragma unroll
    for (int c = 0; c < 4; ++c) {
        if (vals[c] != 0.0f) {
            long f = 4 * i + c;
            int b = (int)(f / V_COLS);
            idx[b] = (int)(f - (long)b * V_COLS);
        }
    }
}

// ---------------------------------------------------------------- NEG fp32 -> bf16 (padded to VPAD rows, zeros)
__global__ void cvt_bf16_kernel(const float4* __restrict__ src, ushort4* __restrict__ dst) {
    int i = blockIdx.x * blockDim.x + threadIdx.x;
    if (i >= N4P) return;
    ushort4 o;
    if (i < N4) {
        float4 v = src[i];
        o.x = f2bf(v.x); o.y = f2bf(v.y); o.z = f2bf(v.z); o.w = f2bf(v.w);
    } else {
        o.x = 0; o.y = 0; o.z = 0; o.w = 0;
    }
    dst[i] = o;
}

// ---------------------------------------------------------------- t[b] = EMBEDM[idx[b]] @ metric  (bf16 out)
__global__ void compute_t_kernel(const float* __restrict__ EMB, const float* __restrict__ metric,
                                 const int* __restrict__ idx, unsigned short* __restrict__ t) {
    __shared__ float erow[E_DIM];
    int b = blockIdx.x, tid = threadIdx.x;
    int id = idx[b];
    erow[tid] = EMB[(long)id * E_DIM + tid];
    __syncthreads();
    float acc = 0.f;
    #pragma unroll 16
    for (int k = 0; k < E_DIM; ++k) acc += erow[k] * metric[k * E_DIM + tid];
    t[b * E_DIM + tid] = f2bf(acc);
}

// ---------------------------------------------------------------- MFMA GEMM: scores = t @ neg^T
// grid (8, NX): x = m-block (128 rows), y = group of TPB n-tiles (128 cols each).
// 256 threads = 4 waves (2x2). A register-resident from global (t is L2-hot).
// B staged per tile via global_load_lds (16B), source-XOR-swizzled so ds_read_b128
// fragment reads are conflict-floor. Stats: online softmax in regs (padded neg rows
// are zero; exp(0 - rowmax) underflows, so no column guards needed).
// Write: 2-chunk LDS roundtrip -> 256B-contiguous wave stores.
template <bool WRITE_OUT>
__global__ __launch_bounds__(256, 2) void gemm_kernel(const unsigned short* __restrict__ t,
                                                      const unsigned short* __restrict__ neg,
                                                      float2* __restrict__ partials,
                                                      const float* __restrict__ lse,
                                                      float* __restrict__ out) {
    __shared__ __align__(16) uint4 Bbuf[2048];       // 32 KB B tile (swizzled 16B chunks)
    __shared__ __align__(16) float sbuf[64 * 132];   // 33.8 KB score chunk (write pass)
    __shared__ float2 stats[2][128];
    __shared__ float lsev[128];

    const int tid  = threadIdx.x;
    const int lane = tid & 63, wave = tid >> 6;
    const int l16  = lane & 15, q = lane >> 4;
    const int wm   = wave >> 1, wn = wave & 1;
    const int mbase = blockIdx.x * 128;
    const int tile0 = blockIdx.y * TPB;

    if (WRITE_OUT && tid < 128) lsev[tid] = lse[mbase + tid];

    // ---- resident A fragments: row = mbase + wm*64 + mf*16 + l16, k = ks*32 + q*8
    short8 af[4][4];
    #pragma unroll
    for (int mf = 0; mf < 4; ++mf) {
        const unsigned short* arow = t + (size_t)(mbase + wm * 64 + mf * 16 + l16) * E_DIM + q * 8;
        #pragma unroll
        for (int ks = 0; ks < 4; ++ks)
            af[mf][ks] = *(const short8*)(arow + ks * 32);
    }

    float rm[4][4], rs[4][4];
    if (!WRITE_OUT) {
        #pragma unroll
        for (int mf = 0; mf < 4; ++mf)
            #pragma unroll
            for (int r = 0; r < 4; ++r) { rm[mf][r] = -1e30f; rs[mf][r] = 0.f; }
    }

    for (int it = 0; it < TPB; ++it) {
        const int tcol = (tile0 + it) * 128;

        // ---- stage B tile: 128 rows x 256 B, source-swizzled so LDS slot
        // (row*16 + cc) holds global chunk (cc ^ (row&15)) of that row.
        {
            const char* gbase = (const char*)(neg + (size_t)tcol * E_DIM);
            char* lbase = (char*)Bbuf + (size_t)(tid & ~63) * 16;   // wave-uniform
            int s = tid;
            #pragma unroll
            for (int j = 0; j < 8; ++j) {
                int row = s >> 4, cc = s & 15;
                int gc = cc ^ (row & 15);
                GLOAD_LDS16(gbase + (size_t)row * 256 + (size_t)gc * 16,
                            lbase + (size_t)j * 4096);
                s += 256;
            }
        }
        __syncthreads();   // stage complete (compiler drains vmcnt)

        // ---- MFMA 128x128 tile, K=128
        floatx4 acc[4][4];
        #pragma unroll
        for (int mf = 0; mf < 4; ++mf)
            #pragma unroll
            for (int nt = 0; nt < 4; ++nt) acc[mf][nt] = (floatx4){0, 0, 0, 0};

        #pragma unroll
        for (int ks = 0; ks < 4; ++ks) {
            short8 bf[4];
            #pragma unroll
            for (int nt = 0; nt < 4; ++nt) {
                int r = wn * 64 + nt * 16 + l16;
                bf[nt] = *(const short8*)&Bbuf[r * 16 + ((ks * 4 + q) ^ (r & 15))];
            }
            #pragma unroll
            for (int mf = 0; mf < 4; ++mf)
                #pragma unroll
                for (int nt = 0; nt < 4; ++nt)
                    acc[mf][nt] = __builtin_amdgcn_mfma_f32_16x16x32_bf16(af[mf][ks], bf[nt], acc[mf][nt], 0, 0, 0);
        }
        __syncthreads();   // all ds_reads done -> Bbuf reusable next tile

        // acc[mf][nt][r]: row = mbase + wm*64 + mf*16 + q*4 + r, col = tcol + wn*64 + nt*16 + l16
        if (!WRITE_OUT) {
            #pragma unroll
            for (int mf = 0; mf < 4; ++mf)
                #pragma unroll
                for (int r = 0; r < 4; ++r) {
                    float a0 = acc[mf][0][r], a1 = acc[mf][1][r];
                    float a2 = acc[mf][2][r], a3 = acc[mf][3][r];
                    float tm = fmaxf(fmaxf(a0, a1), fmaxf(a2, a3));
                    float ts = __expf(a0 - tm) + __expf(a1 - tm) + __expf(a2 - tm) + __expf(a3 - tm);
                    float m = fmaxf(rm[mf][r], tm);
                    rs[mf][r] = rs[mf][r] * __expf(rm[mf][r] - m) + ts * __expf(tm - m);
                    rm[mf][r] = m;
                }
        } else {
            #pragma unroll
            for (int chunk = 0; chunk < 2; ++chunk) {
                if (wm == chunk) {
                    #pragma unroll
                    for (int mf = 0; mf < 4; ++mf)
                        #pragma unroll
                        for (int nt = 0; nt < 4; ++nt)
                            #pragma unroll
                            for (int r = 0; r < 4; ++r)
                                sbuf[(mf * 16 + q * 4 + r) * 132 + wn * 64 + nt * 16 + l16] = acc[mf][nt][r];
                }
                __syncthreads();
                #pragma unroll 4
                for (int j = 0; j < 32; ++j) {
                    int i = j * 256 + tid;
                    int r = i >> 7, c = i & 127;
                    int col = tcol + c;
                    if (col < V_COLS)
                        out[(size_t)(mbase + chunk * 64 + r) * V_COLS + col] = sbuf[r * 132 + c] - lsev[chunk * 64 + r];
                }
                __syncthreads();
            }
        }
    }

    if (!WRITE_OUT) {
        // reduce across the 16 lanes sharing each row (same q, varying l16)
        #pragma unroll
        for (int mf = 0; mf < 4; ++mf)
            #pragma unroll
            for (int r = 0; r < 4; ++r) {
                float m = rm[mf][r], s = rs[mf][r];
                #pragma unroll
                for (int d = 1; d < 16; d <<= 1) {
                    float m2 = __shfl_xor(m, d, 16);
                    float s2 = __shfl_xor(s, d, 16);
                    float mm = fmaxf(m, m2);
                    s = s * __expf(m - mm) + s2 * __expf(m2 - mm);
                    m = mm;
                }
                if (l16 == 0) stats[wn][wm * 64 + mf * 16 + q * 4 + r] = make_float2(m, s);
            }
        __syncthreads();
        if (tid < 128) {
            float2 p0 = stats[0][tid], p1 = stats[1][tid];
            float mm = fmaxf(p0.x, p1.x);
            float ss = p0.y * __expf(p0.x - mm) + p1.y * __expf(p1.x - mm);
            partials[(long)(mbase + tid) * NX + blockIdx.y] = make_float2(mm, ss);
        }
    }
}

// ---------------------------------------------------------------- merge per-block (m,s) partials -> lse[b]
__global__ void merge_lse_kernel(const float2* __restrict__ partials, float* __restrict__ lse) {
    int b = blockIdx.x;
    int tid = threadIdx.x;
    float m = -1e30f, s = 0.f;
    for (int i = tid; i < NX; i += 256) {
        float2 p = partials[(long)b * NX + i];
        float mm = fmaxf(m, p.x);
        s = s * __expf(m - mm) + p.y * __expf(p.x - mm);
        m = mm;
    }
    __shared__ float sm[256], ss[256];
    sm[tid] = m; ss[tid] = s;
    __syncthreads();
    for (int off = 128; off > 0; off >>= 1) {
        if (tid < off) {
            float m1 = sm[tid], s1 = ss[tid];
            float m2 = sm[tid + off], s2 = ss[tid + off];
            float mm = fmaxf(m1, m2);
            sm[tid] = mm;
            ss[tid] = s1 * __expf(m1 - mm) + s2 * __expf(m2 - mm);
        }
        __syncthreads();
    }
    if (tid == 0) lse[b] = sm[0] + __logf(ss[0]);
}

// ---------------------------------------------------------------- launch
extern "C" void kernel_launch(void* const* d_in, const int* in_sizes, int n_in,
                              void* d_out, int out_size, void* d_ws, size_t ws_size,
                              hipStream_t stream) {
    const float* xs     = (const float*)d_in[0];
    const float* metric = (const float*)d_in[1];
    const float* EMB    = (const float*)d_in[2];
    const float* NEG    = (const float*)d_in[3];
    float* out = (float*)d_out;

    char* ws = (char*)d_ws;
    int*            idx      = (int*)ws;                               // 4096 B
    unsigned short* t        = (unsigned short*)(ws + 4096);           // 262144 -> 266240
    unsigned short* neg16    = (unsigned short*)(ws + 266240);         // VPAD*128*2 = 12877824 -> 13144064
    float2*         partials = (float2*)(ws + 13144064);               // 1024*131*8 -> 14217216
    float*          lse      = (float*)(ws + 14217216);                // 4096 B

    {
        long n4 = (long)B_ROWS * V_COLS / 4;
        int blocks = (int)((n4 + 255) / 256);
        find_idx_kernel<<<blocks, 256, 0, stream>>>((const float4*)xs, idx);
    }
    cvt_bf16_kernel<<<(N4P + 255) / 256, 256, 0, stream>>>((const float4*)NEG, (ushort4*)neg16);
    compute_t_kernel<<<B_ROWS, E_DIM, 0, stream>>>(EMB, metric, idx, t);
    gemm_kernel<false><<<dim3(8, NX), 256, 0, stream>>>(t, neg16, partials, nullptr, nullptr);
    merge_lse_kernel<<<B_ROWS, 256, 0, stream>>>(partials, lse);
    gemm_kernel<true><<<dim3(8, NX), 256, 0, stream>>>(t, neg16, partials, lse, out);
}